// Round 1
// baseline (585.670 us; speedup 1.0000x reference)
//
#include <hip/hip_runtime.h>
#include <cstddef>

#define CAPD 64

// Bucket edges by destination: cnt[d] = in-degree, ell[d][0..] = source list.
__global__ void fill_kernel(const int* __restrict__ esrc, const int* __restrict__ edst,
                            int* __restrict__ cnt, int* __restrict__ ell, int E) {
    int e = blockIdx.x * blockDim.x + threadIdx.x;
    if (e >= E) return;
    int d = edst[e];
    int s = esrc[e];
    int pos = atomicAdd(&cnt[d], 1);
    if (pos < CAPD) ell[(size_t)d * CAPD + pos] = s;
}

// isd[i] = 1/sqrt(deg_i), deg_i = 1 + in-degree (self-loop folded in).
__global__ void isd_kernel(const int* __restrict__ cnt, float* __restrict__ isd, int n) {
    int i = blockIdx.x * blockDim.x + threadIdx.x;
    if (i < n) isd[i] = rsqrtf(1.0f + (float)cnt[i]);
}

// T[N,128] = X[N,128] @ W[128,128], f32 vector-ALU GEMM.
// Block 256 threads, tile 128 rows x 128 cols, BK=32, 8x8 register tile.
__global__ __launch_bounds__(256) void gemm128_kernel(const float* __restrict__ X,
                                                      const float* __restrict__ W,
                                                      float* __restrict__ T, int n) {
    __shared__ float xs[32][132];  // xs[k][m], +4 pad keeps 16B alignment, breaks stride conflicts
    __shared__ float ws[32][132];  // ws[k][ncol]
    const int tid = threadIdx.x;
    const int tx = tid & 15;   // col group 0..15
    const int ty = tid >> 4;   // row group 0..15
    const int m0 = blockIdx.x * 128;
    float acc[8][8];
#pragma unroll
    for (int i = 0; i < 8; ++i)
#pragma unroll
        for (int j = 0; j < 8; ++j) acc[i][j] = 0.f;

    const int xr = tid >> 3;         // 0..31: row within pass
    const int xc = (tid & 7) << 2;   // 0..28: k offset (float4)
    const int wr = tid >> 5;         // 0..7 : k row within pass
    const int wc = (tid & 31) << 2;  // 0..124: col offset (float4)

    for (int k0 = 0; k0 < 128; k0 += 32) {
#pragma unroll
        for (int p = 0; p < 4; ++p) {
            int m = xr + p * 32;
            int row = m0 + m;
            float4 v = make_float4(0.f, 0.f, 0.f, 0.f);
            if (row < n) v = *reinterpret_cast<const float4*>(X + (size_t)row * 128 + k0 + xc);
            xs[xc + 0][m] = v.x; xs[xc + 1][m] = v.y;
            xs[xc + 2][m] = v.z; xs[xc + 3][m] = v.w;
        }
#pragma unroll
        for (int p = 0; p < 4; ++p) {
            int k = wr + p * 8;
            float4 v = *reinterpret_cast<const float4*>(W + (size_t)(k0 + k) * 128 + wc);
            *reinterpret_cast<float4*>(&ws[k][wc]) = v;
        }
        __syncthreads();
#pragma unroll
        for (int k = 0; k < 32; ++k) {
            float a[8], b[8];
            *reinterpret_cast<float4*>(&a[0]) = *reinterpret_cast<const float4*>(&xs[k][ty * 8]);
            *reinterpret_cast<float4*>(&a[4]) = *reinterpret_cast<const float4*>(&xs[k][ty * 8 + 4]);
            *reinterpret_cast<float4*>(&b[0]) = *reinterpret_cast<const float4*>(&ws[k][tx * 8]);
            *reinterpret_cast<float4*>(&b[4]) = *reinterpret_cast<const float4*>(&ws[k][tx * 8 + 4]);
#pragma unroll
            for (int i = 0; i < 8; ++i)
#pragma unroll
                for (int j = 0; j < 8; ++j)
                    acc[i][j] = fmaf(a[i], b[j], acc[i][j]);
        }
        __syncthreads();
    }
#pragma unroll
    for (int i = 0; i < 8; ++i) {
        int row = m0 + ty * 8 + i;
        if (row < n) {
            float4 v0 = make_float4(acc[i][0], acc[i][1], acc[i][2], acc[i][3]);
            float4 v1 = make_float4(acc[i][4], acc[i][5], acc[i][6], acc[i][7]);
            *reinterpret_cast<float4*>(T + (size_t)row * 128 + tx * 8) = v0;
            *reinterpret_cast<float4*>(T + (size_t)row * 128 + tx * 8 + 4) = v1;
        }
    }
}

// One wave per node: H[i] = relu( sum_j isd[s_j]*isd[i]*T[s_j] + isd[i]^2*T[i] + bias )
__global__ __launch_bounds__(256) void agg_kernel(const float* __restrict__ T,
                                                  const int* __restrict__ ell,
                                                  const int* __restrict__ cnt,
                                                  const float* __restrict__ isd,
                                                  const float* __restrict__ bias,
                                                  float* __restrict__ H, int n) {
    int gw = (int)((blockIdx.x * 256 + threadIdx.x) >> 6);
    int lane = threadIdx.x & 63;
    if (gw >= n) return;
    float di = isd[gw];
    int c = cnt[gw];
    if (c > CAPD) c = CAPD;
    const float* Ti = T + (size_t)gw * 128;
    float sw = di * di;  // self-loop weight = 1/deg
    float acc0 = Ti[lane] * sw;
    float acc1 = Ti[lane + 64] * sw;
    const int* row = ell + (size_t)gw * CAPD;
    for (int j = 0; j < c; ++j) {
        int s = row[j];
        float w = isd[s] * di;
        const float* Ts = T + (size_t)s * 128;
        acc0 = fmaf(w, Ts[lane], acc0);
        acc1 = fmaf(w, Ts[lane + 64], acc1);
    }
    H[(size_t)gw * 128 + lane] = fmaxf(acc0 + bias[lane], 0.f);
    H[(size_t)gw * 128 + lane + 64] = fmaxf(acc1 + bias[lane + 64], 0.f);
}

// One wave per node: out[i] = sigmoid( dot(H[i], Wout) + bout )
__global__ __launch_bounds__(256) void out_kernel(const float* __restrict__ H,
                                                  const float* __restrict__ Wout,
                                                  const float* __restrict__ bout,
                                                  float* __restrict__ out, int n) {
    int gw = (int)((blockIdx.x * 256 + threadIdx.x) >> 6);
    int lane = threadIdx.x & 63;
    if (gw >= n) return;
    float v = fmaf(H[(size_t)gw * 128 + lane], Wout[lane],
                   H[(size_t)gw * 128 + lane + 64] * Wout[lane + 64]);
#pragma unroll
    for (int off = 32; off > 0; off >>= 1) v += __shfl_xor(v, off, 64);
    if (lane == 0) out[gw] = 1.f / (1.f + expf(-(v + bout[0])));
}

extern "C" void kernel_launch(void* const* d_in, const int* in_sizes, int n_in,
                              void* d_out, int out_size, void* d_ws, size_t ws_size,
                              hipStream_t stream) {
    const float* x    = (const float*)d_in[0];
    const int*   ei   = (const int*)d_in[1];   // [2, E] int32 (JAX demotes int64)
    const float* W1   = (const float*)d_in[2];
    const float* b1   = (const float*)d_in[3];
    const float* W2   = (const float*)d_in[4];
    const float* b2   = (const float*)d_in[5];
    const float* Wout = (const float*)d_in[6];
    const float* bout = (const float*)d_in[7];
    float* out = (float*)d_out;

    const int N = in_sizes[0] / 128;
    const int E = in_sizes[1] / 2;
    const int* esrc = ei;
    const int* edst = ei + E;

    char* p = (char*)d_ws;
    auto alloc = [&](size_t bytes) {
        char* r = p;
        p += (bytes + 255) & ~(size_t)255;
        return (void*)r;
    };
    int*   cnt = (int*)  alloc((size_t)N * 4);
    float* isd = (float*)alloc((size_t)N * 4);
    int*   ell = (int*)  alloc((size_t)N * CAPD * 4);
    float* T   = (float*)alloc((size_t)N * 128 * 4);
    float* H   = (float*)alloc((size_t)N * 128 * 4);

    hipMemsetAsync(cnt, 0, (size_t)N * 4, stream);
    fill_kernel<<<(E + 255) / 256, 256, 0, stream>>>(esrc, edst, cnt, ell, E);
    isd_kernel<<<(N + 255) / 256, 256, 0, stream>>>(cnt, isd, N);

    // Layer 1: T = x@W1 ; H = relu(agg(T) + b1)
    gemm128_kernel<<<(N + 127) / 128, 256, 0, stream>>>(x, W1, T, N);
    agg_kernel<<<(N + 3) / 4, 256, 0, stream>>>(T, ell, cnt, isd, b1, H, N);

    // Layer 2: T = H@W2 ; H = relu(agg(T) + b2)   (agg reads only T -> H overwrite safe)
    gemm128_kernel<<<(N + 127) / 128, 256, 0, stream>>>(H, W2, T, N);
    agg_kernel<<<(N + 3) / 4, 256, 0, stream>>>(T, ell, cnt, isd, b2, H, N);

    // Output head
    out_kernel<<<(N + 3) / 4, 256, 0, stream>>>(H, Wout, bout, out, N);
}

// Round 2
// 496.849 us; speedup vs baseline: 1.1788x; 1.1788x over previous
//
#include <hip/hip_runtime.h>
#include <cstddef>

#define CAPD 64

// Bucket edges by destination: cnt[d] = in-degree, ell[d][0..] = source list.
__global__ void fill_kernel(const int* __restrict__ esrc, const int* __restrict__ edst,
                            int* __restrict__ cnt, int* __restrict__ ell, int E) {
    int e = blockIdx.x * blockDim.x + threadIdx.x;
    if (e >= E) return;
    int d = edst[e];
    int s = esrc[e];
    int pos = atomicAdd(&cnt[d], 1);
    if (pos < CAPD) ell[(size_t)d * CAPD + pos] = s;
}

// isd[i] = 1/sqrt(deg_i), deg_i = 1 + in-degree (self-loop folded in).
__global__ void isd_kernel(const int* __restrict__ cnt, float* __restrict__ isd, int n) {
    int i = blockIdx.x * blockDim.x + threadIdx.x;
    if (i < n) isd[i] = rsqrtf(1.0f + (float)cnt[i]);
}

// Tsc[N,128] = diag(scale) * (X[N,128] @ W[128,128]), f32 vector-ALU GEMM.
// Block 256 threads, tile 128 rows x 128 cols, BK=32, 8x8 register tile.
__global__ __launch_bounds__(256) void gemm128_kernel(const float* __restrict__ X,
                                                      const float* __restrict__ W,
                                                      const float* __restrict__ scale,
                                                      float* __restrict__ T, int n) {
    __shared__ float xs[32][132];
    __shared__ float ws[32][132];
    const int tid = threadIdx.x;
    const int tx = tid & 15;   // col group 0..15
    const int ty = tid >> 4;   // row group 0..15
    const int m0 = blockIdx.x * 128;
    float acc[8][8];
#pragma unroll
    for (int i = 0; i < 8; ++i)
#pragma unroll
        for (int j = 0; j < 8; ++j) acc[i][j] = 0.f;

    const int xr = tid >> 3;         // 0..31: row within pass
    const int xc = (tid & 7) << 2;   // 0..28: k offset (float4)
    const int wr = tid >> 5;         // 0..7 : k row within pass
    const int wc = (tid & 31) << 2;  // 0..124: col offset (float4)

    for (int k0 = 0; k0 < 128; k0 += 32) {
#pragma unroll
        for (int p = 0; p < 4; ++p) {
            int m = xr + p * 32;
            int row = m0 + m;
            float4 v = make_float4(0.f, 0.f, 0.f, 0.f);
            if (row < n) v = *reinterpret_cast<const float4*>(X + (size_t)row * 128 + k0 + xc);
            xs[xc + 0][m] = v.x; xs[xc + 1][m] = v.y;
            xs[xc + 2][m] = v.z; xs[xc + 3][m] = v.w;
        }
#pragma unroll
        for (int p = 0; p < 4; ++p) {
            int k = wr + p * 8;
            float4 v = *reinterpret_cast<const float4*>(W + (size_t)(k0 + k) * 128 + wc);
            *reinterpret_cast<float4*>(&ws[k][wc]) = v;
        }
        __syncthreads();
#pragma unroll
        for (int k = 0; k < 32; ++k) {
            float a[8], b[8];
            *reinterpret_cast<float4*>(&a[0]) = *reinterpret_cast<const float4*>(&xs[k][ty * 8]);
            *reinterpret_cast<float4*>(&a[4]) = *reinterpret_cast<const float4*>(&xs[k][ty * 8 + 4]);
            *reinterpret_cast<float4*>(&b[0]) = *reinterpret_cast<const float4*>(&ws[k][tx * 8]);
            *reinterpret_cast<float4*>(&b[4]) = *reinterpret_cast<const float4*>(&ws[k][tx * 8 + 4]);
#pragma unroll
            for (int i = 0; i < 8; ++i)
#pragma unroll
                for (int j = 0; j < 8; ++j)
                    acc[i][j] = fmaf(a[i], b[j], acc[i][j]);
        }
        __syncthreads();
    }
#pragma unroll
    for (int i = 0; i < 8; ++i) {
        int row = m0 + ty * 8 + i;
        if (row < n) {
            float s = scale[row];
            float4 v0 = make_float4(s * acc[i][0], s * acc[i][1], s * acc[i][2], s * acc[i][3]);
            float4 v1 = make_float4(s * acc[i][4], s * acc[i][5], s * acc[i][6], s * acc[i][7]);
            *reinterpret_cast<float4*>(T + (size_t)row * 128 + tx * 8) = v0;
            *reinterpret_cast<float4*>(T + (size_t)row * 128 + tx * 8 + 4) = v1;
        }
    }
}

// One wave per node. Tsc is pre-scaled by isd[src], so:
//   H[i] = relu( isd[i] * (Tsc[i] + sum_j Tsc[src_j]) + bias )
// (self term: isd[i]*Tsc[i] = isd[i]^2*T[i] = T[i]/deg_i, exactly the reference.)
// Unroll x4 with int4 index loads -> 8 concurrent gather loads in flight.
__global__ __launch_bounds__(256) void agg_kernel(const float* __restrict__ Tsc,
                                                  const int* __restrict__ ell,
                                                  const int* __restrict__ cnt,
                                                  const float* __restrict__ isd,
                                                  const float* __restrict__ bias,
                                                  float* __restrict__ H, int n) {
    int gw = (int)((blockIdx.x * 256 + threadIdx.x) >> 6);
    int lane = threadIdx.x & 63;
    if (gw >= n) return;
    float di = isd[gw];
    int c = cnt[gw];
    if (c > CAPD) c = CAPD;
    const int* row = ell + (size_t)gw * CAPD;
    float acc0 = Tsc[(size_t)gw * 128 + lane];
    float acc1 = Tsc[(size_t)gw * 128 + 64 + lane];
    int j = 0;
    for (; j + 4 <= c; j += 4) {
        int4 s4 = *reinterpret_cast<const int4*>(row + j);  // 16B-aligned (row 256B-aligned, j%4==0)
        const float* p0 = Tsc + (size_t)s4.x * 128;
        const float* p1 = Tsc + (size_t)s4.y * 128;
        const float* p2 = Tsc + (size_t)s4.z * 128;
        const float* p3 = Tsc + (size_t)s4.w * 128;
        float a0 = p0[lane],      a1 = p1[lane],      a2 = p2[lane],      a3 = p3[lane];
        float b0 = p0[lane + 64], b1 = p1[lane + 64], b2 = p2[lane + 64], b3 = p3[lane + 64];
        acc0 += (a0 + a1) + (a2 + a3);
        acc1 += (b0 + b1) + (b2 + b3);
    }
    for (; j < c; ++j) {
        int s = row[j];
        acc0 += Tsc[(size_t)s * 128 + lane];
        acc1 += Tsc[(size_t)s * 128 + 64 + lane];
    }
    H[(size_t)gw * 128 + lane]      = fmaxf(fmaf(di, acc0, bias[lane]), 0.f);
    H[(size_t)gw * 128 + lane + 64] = fmaxf(fmaf(di, acc1, bias[lane + 64]), 0.f);
}

// One wave per node: out[i] = sigmoid( dot(H[i], Wout) + bout )
__global__ __launch_bounds__(256) void out_kernel(const float* __restrict__ H,
                                                  const float* __restrict__ Wout,
                                                  const float* __restrict__ bout,
                                                  float* __restrict__ out, int n) {
    int gw = (int)((blockIdx.x * 256 + threadIdx.x) >> 6);
    int lane = threadIdx.x & 63;
    if (gw >= n) return;
    float v = fmaf(H[(size_t)gw * 128 + lane], Wout[lane],
                   H[(size_t)gw * 128 + lane + 64] * Wout[lane + 64]);
#pragma unroll
    for (int off = 32; off > 0; off >>= 1) v += __shfl_xor(v, off, 64);
    if (lane == 0) out[gw] = 1.f / (1.f + expf(-(v + bout[0])));
}

extern "C" void kernel_launch(void* const* d_in, const int* in_sizes, int n_in,
                              void* d_out, int out_size, void* d_ws, size_t ws_size,
                              hipStream_t stream) {
    const float* x    = (const float*)d_in[0];
    const int*   ei   = (const int*)d_in[1];   // [2, E] int32 (JAX demotes int64)
    const float* W1   = (const float*)d_in[2];
    const float* b1   = (const float*)d_in[3];
    const float* W2   = (const float*)d_in[4];
    const float* b2   = (const float*)d_in[5];
    const float* Wout = (const float*)d_in[6];
    const float* bout = (const float*)d_in[7];
    float* out = (float*)d_out;

    const int N = in_sizes[0] / 128;
    const int E = in_sizes[1] / 2;
    const int* esrc = ei;
    const int* edst = ei + E;

    char* p = (char*)d_ws;
    auto alloc = [&](size_t bytes) {
        char* r = p;
        p += (bytes + 255) & ~(size_t)255;
        return (void*)r;
    };
    int*   cnt = (int*)  alloc((size_t)N * 4);
    float* isd = (float*)alloc((size_t)N * 4);
    int*   ell = (int*)  alloc((size_t)N * CAPD * 4);
    float* T   = (float*)alloc((size_t)N * 128 * 4);
    float* H   = (float*)alloc((size_t)N * 128 * 4);

    hipMemsetAsync(cnt, 0, (size_t)N * 4, stream);
    fill_kernel<<<(E + 255) / 256, 256, 0, stream>>>(esrc, edst, cnt, ell, E);
    isd_kernel<<<(N + 255) / 256, 256, 0, stream>>>(cnt, isd, N);

    // Layer 1: T = diag(isd)*(x@W1) ; H = relu(isd*(T_self + sum T_src) + b1)
    gemm128_kernel<<<(N + 127) / 128, 256, 0, stream>>>(x, W1, isd, T, N);
    agg_kernel<<<(N + 3) / 4, 256, 0, stream>>>(T, ell, cnt, isd, b1, H, N);

    // Layer 2 (agg reads only T -> overwriting H is safe)
    gemm128_kernel<<<(N + 127) / 128, 256, 0, stream>>>(H, W2, isd, T, N);
    agg_kernel<<<(N + 3) / 4, 256, 0, stream>>>(T, ell, cnt, isd, b2, H, N);

    // Output head
    out_kernel<<<(N + 3) / 4, 256, 0, stream>>>(H, Wout, bout, out, N);
}